// Round 8
// baseline (248.654 us; speedup 1.0000x reference)
//
#include <hip/hip_runtime.h>
#include <hip/hip_bf16.h>
#include <math.h>

typedef short short8_t __attribute__((ext_vector_type(8)));
typedef float floatx4  __attribute__((ext_vector_type(4)));
typedef float floatx2  __attribute__((ext_vector_type(2)));
typedef unsigned int uint;

#define EPB 1024   // edges per histogram/scatter block
#define BSH 9      // 512 nodes per coarse bucket

// ---------------- bf16 helpers (RNE) ----------------------------------------

__device__ inline unsigned short f2b(float f) {
    uint u = __float_as_uint(f);
    u += 0x7fff + ((u >> 16) & 1);
    return (unsigned short)(u >> 16);
}
__device__ inline uint pack2(float a, float b) {
    return (uint)f2b(a) | ((uint)f2b(b) << 16);
}

// ---------------- fp8 (e4m3) helpers -----------------------------------------

__device__ inline uint enc4_fp8(float f0, float f1, float f2, float f3) {
    uint v = __builtin_amdgcn_cvt_pk_fp8_f32(f0, f1, 0, false);
    v = __builtin_amdgcn_cvt_pk_fp8_f32(f2, f3, v, true);
    return v;
}
__device__ inline unsigned char enc1_fp8(float f) {
    return (unsigned char)(__builtin_amdgcn_cvt_pk_fp8_f32(f, f, 0, false) & 0xff);
}

// Lesson ledger:
//  R10/R13: GLOBAL atomic histogram (1 atomic/edge) pinned ~43-50us. LDS hist
//       + few global atomics per block is the pattern that works.
//  R12: co-scheduling light branches in one grid is free.
//  R11/R14/R15: a latency-bound phase inherits a fused kernel's worst-phase
//       occupancy — per-BLOCK fusion of gather into MFMA collapsed (139us).
//  R9: keep scatter targets packed (L2-resident).
//  R17 (FAILED): coop grid.sync costs ~350us EACH on 8-XCD gfx950. Never.
//  R18 (FAILED): device-scope fences/tickets per block are mini grid.syncs.
//  R20: gathers -> 1 node per lane-group (no shfl reduce): 256 -> 230us.
//  R21 (FAILED): CAP-region cursor CSR: -1 dispatch but +8.5us — 2x sparse
//       ebuf/csr (16 MB, gapped) broke L2 packing of scatter writes (R9
//       again). Dispatch overhead is smaller than sparse-region cache cost.
//       CSR chain reverted to R20 form.
//  R22 (this round): linear occupancy fix — stage ONLY agg in LDS (K=128:
//       69.6->34.8 KB, 2->4 blocks/CU); xin A-fragments read direct from
//       global (16 rows x 64 B contiguous per wave, L2-resident, 4x reuse).
//       Gathers: 4-deep unrolled edge loop (4 loads in flight per lane).

// ---------------- shared device phase bodies ---------------------------------

__device__ inline void scan256(int* ss, int t) {
#pragma unroll
    for (int off = 1; off < 256; off <<= 1) {
        int u = (t >= off) ? ss[t - off] : 0;
        __syncthreads();
        ss[t] += u;
        __syncthreads();
    }
}

// phase A: hist | cvt_x | cvt_w | zero(pooled) | gstart
__global__ __launch_bounds__(256) void k_phase_a(
    const int* __restrict__ dst, int* __restrict__ bhist, int E,
    const float* __restrict__ x, unsigned short* __restrict__ xb,
    unsigned char* __restrict__ xf8, int nX,
    const float* __restrict__ Wl1, const float* __restrict__ Wr1,
    const float* __restrict__ Wl2, const float* __restrict__ Wr2,
    unsigned short* __restrict__ wbuf,
    float* __restrict__ pooled,
    const int* __restrict__ batch, int* __restrict__ gstart, int N, int G,
    int bHist, int bCvtX, int bCvtW, int bZero) {
    __shared__ int h[256];
    int b = blockIdx.x;
    int tid = threadIdx.x;
    if (b < bHist) {
        h[tid] = 0;
        __syncthreads();
        int e = b * EPB + tid * 4;
        if (e + 3 < E) {
            int4 d4 = *(const int4*)(dst + e);
            atomicAdd(&h[d4.x >> BSH], 1);
            atomicAdd(&h[d4.y >> BSH], 1);
            atomicAdd(&h[d4.z >> BSH], 1);
            atomicAdd(&h[d4.w >> BSH], 1);
        } else {
            for (int k = e; k < E; ++k) atomicAdd(&h[dst[k] >> BSH], 1);
        }
        __syncthreads();
        bhist[(size_t)b * 256 + tid] = h[tid];
    } else if (b < bHist + bCvtX) {
        int i = ((b - bHist) * 256 + tid) * 8;
        if (i < nX) {
            float4 v0 = *(const float4*)(x + i);
            float4 v1 = *(const float4*)(x + i + 4);
            uint4 ob;
            ob.x = pack2(v0.x, v0.y);
            ob.y = pack2(v0.z, v0.w);
            ob.z = pack2(v1.x, v1.y);
            ob.w = pack2(v1.z, v1.w);
            *(uint4*)(xb + i) = ob;
            uint2 of;
            of.x = enc4_fp8(v0.x, v0.y, v0.z, v0.w);
            of.y = enc4_fp8(v1.x, v1.y, v1.z, v1.w);
            *(uint2*)(xf8 + i) = of;
        }
    } else if (b < bHist + bCvtX + bCvtW) {
        int i = (b - bHist - bCvtX) * 256 + tid;
        if (i < 49152) {
            float v;
            if (i < 8192)       v = Wl1[i];
            else if (i < 16384) v = Wr1[i - 8192];
            else if (i < 32768) v = Wl2[i - 16384];
            else                v = Wr2[i - 32768];
            wbuf[i] = f2b(v);
        }
    } else if (b < bHist + bCvtX + bCvtW + bZero) {
        // zero pooled[256][128] (32768 floats) — consumed by linear2 atomics
        int i = ((b - bHist - bCvtX - bCvtW) * 256 + tid) * 4;
        float4 z = make_float4(0.f, 0.f, 0.f, 0.f);
        *(float4*)(pooled + i) = z;
    } else {
        for (int g = tid; g <= G; g += 256) {
            if (g == G) { gstart[G] = N; continue; }
            int lo = 0, hi = N;
            while (lo < hi) {
                int mid = (lo + hi) >> 1;
                if (batch[mid] < g) lo = mid + 1; else hi = mid;
            }
            gstart[g] = lo;
        }
    }
}

// column scan: for bucket k, exclusive-prefix bhist[:,k] over blocks; btot[k]=total
__global__ __launch_bounds__(256) void k_scan_bh(int* __restrict__ bhist,
                                                 int* __restrict__ btot, int nb) {
    __shared__ int ss[256];
    int k = blockIdx.x;
    int t = threadIdx.x;
    int b0 = t * 4;
    int v[4];
    int sum = 0;
#pragma unroll
    for (int i = 0; i < 4; ++i) {
        int b = b0 + i;
        v[i] = (b < nb) ? bhist[(size_t)b * 256 + k] : 0;
        sum += v[i];
    }
    ss[t] = sum;
    __syncthreads();
    scan256(ss, t);
    int run = ss[t] - sum;
#pragma unroll
    for (int i = 0; i < 4; ++i) {
        int b = b0 + i;
        if (b < nb) { bhist[(size_t)b * 256 + k] = run; run += v[i]; }
    }
    if (t == 0) btot[k] = ss[255];
}

// scatter edges into bucket-grouped ebuf; positions via LDS cursors.
// bucket bases recomputed locally from btot. record = (dst&511)<<23 | src
__global__ __launch_bounds__(256) void k_scatter_b(
    const int* __restrict__ src, const int* __restrict__ dst,
    const int* __restrict__ bhist, const int* __restrict__ btot,
    int* __restrict__ ebuf, int E) {
    __shared__ int ss[256];
    __shared__ int lbase[256];
    int b = blockIdx.x;
    int t = threadIdx.x;
    int v = btot[t];
    ss[t] = v;
    __syncthreads();
    scan256(ss, t);
    lbase[t] = (ss[t] - v) + bhist[(size_t)b * 256 + t];
    __syncthreads();
    int e = b * EPB + t * 4;
    if (e + 3 < E) {
        int4 d4 = *(const int4*)(dst + e);
        int4 s4 = *(const int4*)(src + e);
        int k, p;
        k = d4.x >> BSH; p = atomicAdd(&lbase[k], 1); ebuf[p] = ((d4.x & 511) << 23) | s4.x;
        k = d4.y >> BSH; p = atomicAdd(&lbase[k], 1); ebuf[p] = ((d4.y & 511) << 23) | s4.y;
        k = d4.z >> BSH; p = atomicAdd(&lbase[k], 1); ebuf[p] = ((d4.z & 511) << 23) | s4.z;
        k = d4.w >> BSH; p = atomicAdd(&lbase[k], 1); ebuf[p] = ((d4.w & 511) << 23) | s4.w;
    } else {
        for (int q = e; q < E; ++q) {
            int d = dst[q];
            int p = atomicAdd(&lbase[d >> BSH], 1);
            ebuf[p] = ((d & 511) << 23) | src[q];
        }
    }
}

// per-bucket counting sort: 512-bin LDS histogram + scan -> row_start + csr_src
__global__ __launch_bounds__(256) void k_bucket_csr(
    const int* __restrict__ ebuf, const int* __restrict__ btot,
    int* __restrict__ row_start, int* __restrict__ csr_src, int N, int NB) {
    __shared__ int ss[256];
    __shared__ int bbS[257];
    __shared__ int h2[512];
    int k = blockIdx.x;
    int t = threadIdx.x;
    int v = btot[t];
    ss[t] = v;
    __syncthreads();
    scan256(ss, t);
    bbS[t] = ss[t] - v;
    if (t == 255) bbS[256] = ss[255];
    __syncthreads();
    int s = bbS[k], e = bbS[k + 1];
    int node0 = k << BSH;
    int nn = N - node0; if (nn > 512) nn = 512;
    if (k == NB - 1 && t == 0) row_start[node0 + nn] = e;
    h2[t] = 0; h2[t + 256] = 0;
    __syncthreads();
    for (int i = s + t; i < e; i += 256)
        atomicAdd(&h2[((uint)ebuf[i]) >> 23], 1);
    __syncthreads();
    int a0 = h2[2 * t], a1 = h2[2 * t + 1];
    int ps = a0 + a1;
    ss[t] = ps;
    __syncthreads();
    scan256(ss, t);
    int base = ss[t] - ps;
    h2[2 * t] = base;
    h2[2 * t + 1] = base + a0;
    __syncthreads();
    int rs0 = h2[t];
    int rs1 = h2[t + 256];
    __syncthreads();
    if (t < nn)       row_start[node0 + t]       = s + rs0;
    if (t + 256 < nn) row_start[node0 + t + 256] = s + rs1;
    for (int i = s + t; i < e; i += 256) {
        int rec = ebuf[i];
        int j = ((uint)rec) >> 23;
        int pos = atomicAdd(&h2[j], 1);
        csr_src[s + pos] = rec & 0x7FFFFF;
    }
}

// ---------------- mean aggregation (fp8 in, bf16 out, fp32 accumulate) -------
// R20: 1 node per LANE-GROUP: no cross-lane reduce, every lane packs/stores
// its own 8 outputs. R22: 4-deep unrolled edge loop (4 loads in flight).

#define ACCF8(v)                                                        \
    { floatx2 f = __builtin_amdgcn_cvt_pk_f32_fp8((v).x, false);        \
      a[0] += f[0]; a[1] += f[1];                                       \
      f = __builtin_amdgcn_cvt_pk_f32_fp8((v).x, true);                 \
      a[2] += f[0]; a[3] += f[1];                                       \
      f = __builtin_amdgcn_cvt_pk_f32_fp8((v).y, false);                \
      a[4] += f[0]; a[5] += f[1];                                       \
      f = __builtin_amdgcn_cvt_pk_f32_fp8((v).y, true);                 \
      a[6] += f[0]; a[7] += f[1]; }

// K=64: 8 lanes per node (8B each), 32 nodes per 256-thread block.
__global__ void k_gather1(const unsigned char* __restrict__ xf8,
                          const int* __restrict__ row_start,
                          const int* __restrict__ csr_src,
                          unsigned short* __restrict__ agg, int n_nodes) {
    int tid = threadIdx.x;
    int node = blockIdx.x * 32 + (tid >> 3);
    if (node >= n_nodes) return;
    int lp = tid & 7;
    int s = row_start[node];
    int e = row_start[node + 1];
    float a[8];
#pragma unroll
    for (int q = 0; q < 8; ++q) a[q] = 0.f;
    int i = s;
    for (; i + 3 < e; i += 4) {
        int u0 = csr_src[i];
        int u1 = csr_src[i + 1];
        int u2 = csr_src[i + 2];
        int u3 = csr_src[i + 3];
        uint2 v0 = *(const uint2*)(xf8 + (size_t)u0 * 64 + lp * 8);
        uint2 v1 = *(const uint2*)(xf8 + (size_t)u1 * 64 + lp * 8);
        uint2 v2 = *(const uint2*)(xf8 + (size_t)u2 * 64 + lp * 8);
        uint2 v3 = *(const uint2*)(xf8 + (size_t)u3 * 64 + lp * 8);
        ACCF8(v0);
        ACCF8(v1);
        ACCF8(v2);
        ACCF8(v3);
    }
    for (; i < e; ++i) {
        int u0 = csr_src[i];
        uint2 v0 = *(const uint2*)(xf8 + (size_t)u0 * 64 + lp * 8);
        ACCF8(v0);
    }
    int d = e - s;
    float scale = (d > 0) ? (1.f / (float)d) : 1.f;
    uint4 o;
    o.x = pack2(a[0] * scale, a[1] * scale);
    o.y = pack2(a[2] * scale, a[3] * scale);
    o.z = pack2(a[4] * scale, a[5] * scale);
    o.w = pack2(a[6] * scale, a[7] * scale);
    *(uint4*)(agg + (size_t)node * 64 + lp * 8) = o;
}

// K=128: 16 lanes per node (8B each), 16 nodes per 256-thread block.
__global__ void k_gather2(const unsigned char* __restrict__ h1f8,
                          const int* __restrict__ row_start,
                          const int* __restrict__ csr_src,
                          unsigned short* __restrict__ agg, int n_nodes) {
    int tid = threadIdx.x;
    int node = blockIdx.x * 16 + (tid >> 4);
    if (node >= n_nodes) return;
    int lp = tid & 15;
    int s = row_start[node];
    int e = row_start[node + 1];
    float a[8];
#pragma unroll
    for (int q = 0; q < 8; ++q) a[q] = 0.f;
    int i = s;
    for (; i + 3 < e; i += 4) {
        int u0 = csr_src[i];
        int u1 = csr_src[i + 1];
        int u2 = csr_src[i + 2];
        int u3 = csr_src[i + 3];
        uint2 v0 = *(const uint2*)(h1f8 + (size_t)u0 * 128 + lp * 8);
        uint2 v1 = *(const uint2*)(h1f8 + (size_t)u1 * 128 + lp * 8);
        uint2 v2 = *(const uint2*)(h1f8 + (size_t)u2 * 128 + lp * 8);
        uint2 v3 = *(const uint2*)(h1f8 + (size_t)u3 * 128 + lp * 8);
        ACCF8(v0);
        ACCF8(v1);
        ACCF8(v2);
        ACCF8(v3);
    }
    for (; i < e; ++i) {
        int u0 = csr_src[i];
        uint2 v0 = *(const uint2*)(h1f8 + (size_t)u0 * 128 + lp * 8);
        ACCF8(v0);
    }
    int d = e - s;
    float scale = (d > 0) ? (1.f / (float)d) : 1.f;
    uint4 o;
    o.x = pack2(a[0] * scale, a[1] * scale);
    o.y = pack2(a[2] * scale, a[3] * scale);
    o.z = pack2(a[4] * scale, a[5] * scale);
    o.w = pack2(a[6] * scale, a[7] * scale);
    *(uint4*)(agg + (size_t)node * 128 + lp * 8) = o;
}

// ---------------- MFMA SAGE linear: relu(agg@Wl.T + bl + xin@Wr.T) ----------
// R22: stage ONLY agg in LDS (halves LDS -> 4 blocks/CU at K=128); xin
// A-fragments read directly from global (16 rows x 64 B contiguous per wave,
// 4x L2-resident reuse within block). Rows padded to K+8 shorts (bank spread).
// POOL=false: emit bf16 h + fp8 copy. POOL=true: R2-validated epilogue —
// per-thread running per-graph sums + atomicAdd into pooled[G][128].

template <int K, bool POOL>
__global__ __launch_bounds__(256) void k_linear_mfma(
    const unsigned short* __restrict__ aggA, const unsigned short* __restrict__ xinA,
    const unsigned short* __restrict__ Wlb,  const float* __restrict__ bl,
    const unsigned short* __restrict__ Wrb,  unsigned short* __restrict__ out,
    unsigned char* __restrict__ outf8,
    const int* __restrict__ batch, float* __restrict__ pooled, int n_nodes) {
    constexpr int KH = K / 32;             // K-chunks per operand half
    constexpr int KP = K + 8;              // padded row (shorts)
    constexpr int SLOTS = K / 8;           // uint4 slots per row
    __shared__ __align__(16) short As[128 * KP];  // K=64: 18.4KB, K=128: 34.8KB
    __shared__ int bb[128];

    int tid  = threadIdx.x;
    int lane = tid & 63;
    int wave = tid >> 6;
    int quad = lane >> 4;
    int lr   = lane & 15;
    int node0 = blockIdx.x * 128;

    if (POOL && tid < 128) {
        int n = node0 + tid;
        bb[tid] = (n < n_nodes) ? batch[n] : 0;
    }

    // ---- stage agg tile only, all loads in flight, one barrier --------------
#pragma unroll
    for (int idx = tid; idx < 128 * SLOTS; idx += 256) {
        int row  = idx / SLOTS;
        int slot = idx % SLOTS;
        int n = node0 + row; if (n >= n_nodes) n = n_nodes - 1;
        uint4 va = *(const uint4*)(aggA + (size_t)n * K + slot * 8);
        *(uint4*)(&As[row * KP + slot * 8]) = va;
    }
    __syncthreads();

    floatx4 acc[8][2];
#pragma unroll
    for (int mi = 0; mi < 8; ++mi)
#pragma unroll
        for (int ni = 0; ni < 2; ++ni)
            acc[mi][ni] = (floatx4){0.f, 0.f, 0.f, 0.f};

    // agg half (Wl): A-fragments from LDS
#pragma unroll
    for (int c = 0; c < KH; ++c) {
        short8_t bfrag[2];
#pragma unroll
        for (int ni = 0; ni < 2; ++ni) {
            int j = wave * 32 + ni * 16 + lr;
            bfrag[ni] = *(const short8_t*)(Wlb + (size_t)j * K + c * 32 + quad * 8);
        }
#pragma unroll
        for (int mi = 0; mi < 8; ++mi) {
            short8_t af = *(const short8_t*)(&As[(mi * 16 + lr) * KP + c * 32 + quad * 8]);
            acc[mi][0] = __builtin_amdgcn_mfma_f32_16x16x32_bf16(af, bfrag[0], acc[mi][0], 0, 0, 0);
            acc[mi][1] = __builtin_amdgcn_mfma_f32_16x16x32_bf16(af, bfrag[1], acc[mi][1], 0, 0, 0);
        }
    }

    // xin half (Wr): A-fragments direct from global (L2-resident, 4x reuse)
#pragma unroll
    for (int c = 0; c < KH; ++c) {
        short8_t bfrag[2];
#pragma unroll
        for (int ni = 0; ni < 2; ++ni) {
            int j = wave * 32 + ni * 16 + lr;
            bfrag[ni] = *(const short8_t*)(Wrb + (size_t)j * K + c * 32 + quad * 8);
        }
#pragma unroll
        for (int mi = 0; mi < 8; ++mi) {
            int n = node0 + mi * 16 + lr; if (n >= n_nodes) n = n_nodes - 1;
            short8_t af = *(const short8_t*)(xinA + (size_t)n * K + c * 32 + quad * 8);
            acc[mi][0] = __builtin_amdgcn_mfma_f32_16x16x32_bf16(af, bfrag[0], acc[mi][0], 0, 0, 0);
            acc[mi][1] = __builtin_amdgcn_mfma_f32_16x16x32_bf16(af, bfrag[1], acc[mi][1], 0, 0, 0);
        }
    }

    float b0 = bl[wave * 32 + lr];
    float b1 = bl[wave * 32 + 16 + lr];
    int j0 = wave * 32 + lr;

    if (!POOL) {
#pragma unroll
        for (int mi = 0; mi < 8; ++mi) {
#pragma unroll
            for (int r = 0; r < 4; ++r) {
                int node = node0 + mi * 16 + quad * 4 + r;
                if (node < n_nodes) {
                    float v0 = fmaxf(acc[mi][0][r] + b0, 0.f);
                    float v1 = fmaxf(acc[mi][1][r] + b1, 0.f);
                    out[(size_t)node * 128 + j0]      = f2b(v0);
                    out[(size_t)node * 128 + j0 + 16] = f2b(v1);
                    outf8[(size_t)node * 128 + j0]      = enc1_fp8(v0);
                    outf8[(size_t)node * 128 + j0 + 16] = enc1_fp8(v1);
                }
            }
        }
    } else {
        // R2-validated: thread's nodes are monotone -> running per-graph sums,
        // flush on boundary; ~1-2 graphs per 128-node window (batch sorted).
        int gcur = -1;
        float s0 = 0.f, s1 = 0.f;
#pragma unroll
        for (int mi = 0; mi < 8; ++mi) {
#pragma unroll
            for (int r = 0; r < 4; ++r) {
                int li = mi * 16 + quad * 4 + r;
                int node = node0 + li;
                if (node < n_nodes) {
                    float v0 = fmaxf(acc[mi][0][r] + b0, 0.f);
                    float v1 = fmaxf(acc[mi][1][r] + b1, 0.f);
                    int g = bb[li];
                    if (g != gcur) {
                        if (gcur >= 0) {
                            atomicAdd(&pooled[gcur * 128 + j0], s0);
                            atomicAdd(&pooled[gcur * 128 + j0 + 16], s1);
                        }
                        gcur = g; s0 = 0.f; s1 = 0.f;
                    }
                    s0 += v0;
                    s1 += v1;
                }
            }
        }
        if (gcur >= 0) {
            atomicAdd(&pooled[gcur * 128 + j0], s0);
            atomicAdd(&pooled[gcur * 128 + j0 + 16], s1);
        }
    }
}

// ---------------- tiny head: mean + linear + log_softmax ---------------------

__global__ void k_head(const float* __restrict__ pooled,
                       const int* __restrict__ gstart,
                       const float* __restrict__ Wout,
                       const float* __restrict__ bout,
                       float* __restrict__ out) {
    int g = blockIdx.x;
    int lane = threadIdx.x;  // 64
    float p0 = pooled[g * 128 + lane];
    float p1 = pooled[g * 128 + 64 + lane];
    float d0 = p0 * Wout[lane] + p1 * Wout[64 + lane];
    float d1 = p0 * Wout[128 + lane] + p1 * Wout[192 + lane];
#pragma unroll
    for (int m = 32; m > 0; m >>= 1) {
        d0 += __shfl_xor(d0, m);
        d1 += __shfl_xor(d1, m);
    }
    if (lane == 0) {
        float cnt = (float)(gstart[g + 1] - gstart[g]);
        float inv = (cnt > 0.f) ? (1.f / cnt) : 1.f;
        float l0 = d0 * inv + bout[0];
        float l1 = d1 * inv + bout[1];
        float mx = fmaxf(l0, l1);
        float lse = mx + logf(expf(l0 - mx) + expf(l1 - mx));
        out[g * 2 + 0] = l0 - lse;
        out[g * 2 + 1] = l1 - lse;
    }
}

// ---------------- launch -----------------------------------------------------

static inline size_t alignUp(size_t x, size_t a) { return (x + a - 1) & ~(a - 1); }

extern "C" void kernel_launch(void* const* d_in, const int* in_sizes, int n_in,
                              void* d_out, int out_size, void* d_ws, size_t ws_size,
                              hipStream_t stream) {
    const float* x    = (const float*)d_in[0];
    const int*   ei   = (const int*)d_in[1];
    const int*   batch= (const int*)d_in[2];
    const float* Wl1  = (const float*)d_in[3];
    const float* bl1  = (const float*)d_in[4];
    const float* Wr1  = (const float*)d_in[5];
    const float* Wl2  = (const float*)d_in[6];
    const float* bl2  = (const float*)d_in[7];
    const float* Wr2  = (const float*)d_in[8];
    const float* Wout = (const float*)d_in[9];
    const float* bout = (const float*)d_in[10];
    float* out = (float*)d_out;

    const int N = in_sizes[0] / 64;   // 100000 (must be < 2^23 for record packing)
    const int E = in_sizes[1] / 2;    // 1000000
    const int G = out_size / 2;       // 256

    const int* src = ei;
    const int* dst = ei + E;

    const int bHist = (E + EPB - 1) / EPB;     // 977
    const int NB    = (N + 511) >> BSH;        // 196 coarse buckets
    const int bCvtX = (N * 64 / 8 + 255) / 256;
    const int bCvtW = 192;
    const int bZero = (G * 128 / 4 + 255) / 256;    // 32

    // workspace layout
    char* ws = (char*)d_ws;
    size_t off = 0;
    int*   bhist     = (int*)(ws + off); off = alignUp(off + (size_t)bHist * 256 * 4, 256);
    int*   btot      = (int*)(ws + off); off = alignUp(off + (size_t)257 * 4, 256);
    int*   row_start = (int*)(ws + off); off = alignUp(off + (size_t)(N + 1) * 4, 256);
    int*   ebuf      = (int*)(ws + off); off = alignUp(off + (size_t)E * 4, 256);
    int*   csr_src   = (int*)(ws + off); off = alignUp(off + (size_t)E * 4, 256);
    int*   gstart    = (int*)(ws + off); off = alignUp(off + (size_t)(G + 1) * 4, 256);
    unsigned short* xb   = (unsigned short*)(ws + off); off = alignUp(off + (size_t)N * 64 * 2, 256);
    unsigned char*  xf8  = (unsigned char*)(ws + off);  off = alignUp(off + (size_t)N * 64, 256);
    unsigned short* wbuf = (unsigned short*)(ws + off); off = alignUp(off + (size_t)49152 * 2, 256);
    unsigned short* agg1 = (unsigned short*)(ws + off); off = alignUp(off + (size_t)N * 64 * 2, 256);
    unsigned short* h1   = (unsigned short*)(ws + off); off = alignUp(off + (size_t)N * 128 * 2, 256);
    unsigned char*  h1f8 = (unsigned char*)(ws + off);  off = alignUp(off + (size_t)N * 128, 256);
    unsigned short* agg2 = (unsigned short*)(ws + off); off = alignUp(off + (size_t)N * 128 * 2, 256);
    float*          pooled = (float*)(ws + off); off = alignUp(off + (size_t)G * 128 * 4, 256);
    (void)ws_size;

    unsigned short* Wl1b = wbuf;
    unsigned short* Wr1b = wbuf + 8192;
    unsigned short* Wl2b = wbuf + 16384;
    unsigned short* Wr2b = wbuf + 32768;

    // phase A: LDS bucket histogram + cvt_x + cvt_w + zero(pooled) + graph bounds
    k_phase_a<<<bHist + bCvtX + bCvtW + bZero + 1, 256, 0, stream>>>(
        dst, bhist, E,
        x, xb, xf8, N * 64,
        Wl1, Wr1, Wl2, Wr2, wbuf,
        pooled,
        batch, gstart, N, G,
        bHist, bCvtX, bCvtW, bZero);

    // bucket scans + bucket-grouped scatter + per-bucket counting sort
    k_scan_bh<<<256, 256, 0, stream>>>(bhist, btot, bHist);
    k_scatter_b<<<bHist, 256, 0, stream>>>(src, dst, bhist, btot, ebuf, E);
    k_bucket_csr<<<NB, 256, 0, stream>>>(ebuf, btot, row_start, csr_src, N, NB);

    // layer 1: gather (fp8) -> MFMA linear (emits h1 bf16 + h1f8 fp8)
    k_gather1<<<(N + 31) / 32, 256, 0, stream>>>(xf8, row_start, csr_src, agg1, N);
    k_linear_mfma<64, false><<<(N + 127) / 128, 256, 0, stream>>>(
        agg1, xb, Wl1b, bl1, Wr1b, h1, h1f8, nullptr, nullptr, N);

    // layer 2: gather -> MFMA linear + per-graph pool (fp32 atomics)
    k_gather2<<<(N + 15) / 16, 256, 0, stream>>>(h1f8, row_start, csr_src, agg2, N);
    k_linear_mfma<128, true><<<(N + 127) / 128, 256, 0, stream>>>(
        agg2, h1, Wl2b, bl2, Wr2b, nullptr, nullptr, batch, pooled, N);

    // tiny head: mean + 128->2 linear + log_softmax
    k_head<<<G, 64, 0, stream>>>(pooled, gstart, Wout, bout, out);
}

// Round 9
// 237.914 us; speedup vs baseline: 1.0451x; 1.0451x over previous
//
#include <hip/hip_runtime.h>
#include <hip/hip_bf16.h>
#include <math.h>

typedef short short8_t __attribute__((ext_vector_type(8)));
typedef float floatx4  __attribute__((ext_vector_type(4)));
typedef float floatx2  __attribute__((ext_vector_type(2)));
typedef unsigned int uint;

#define EPB 1024   // edges per histogram/scatter block
#define BSH 9      // 512 nodes per coarse bucket

// ---------------- bf16 helpers (RNE) ----------------------------------------

__device__ inline unsigned short f2b(float f) {
    uint u = __float_as_uint(f);
    u += 0x7fff + ((u >> 16) & 1);
    return (unsigned short)(u >> 16);
}
__device__ inline uint pack2(float a, float b) {
    return (uint)f2b(a) | ((uint)f2b(b) << 16);
}

// ---------------- fp8 (e4m3) helpers -----------------------------------------

__device__ inline uint enc4_fp8(float f0, float f1, float f2, float f3) {
    uint v = __builtin_amdgcn_cvt_pk_fp8_f32(f0, f1, 0, false);
    v = __builtin_amdgcn_cvt_pk_fp8_f32(f2, f3, v, true);
    return v;
}
__device__ inline unsigned char enc1_fp8(float f) {
    return (unsigned char)(__builtin_amdgcn_cvt_pk_fp8_f32(f, f, 0, false) & 0xff);
}

// Lesson ledger:
//  R10/R13: GLOBAL atomic histogram pinned ~43-50us. LDS hist + few global
//       atomics per block is the pattern that works.
//  R12: co-scheduling light branches in one grid is free.
//  R11/R14/R15: a latency-bound phase inherits a fused kernel's worst-phase
//       occupancy — per-BLOCK fusion of gather into MFMA collapsed (139us).
//  R9/R21: keep scatter targets PACKED. Sparse/gapped regions re-trigger
//       write amp; dispatch overhead < sparse-region cache cost.
//  R17 (FAILED): coop grid.sync ~350us EACH on 8-XCD gfx950. Never.
//  R18 (FAILED): device-scope fences/tickets per block are mini grid.syncs.
//  R20: gathers -> 1 node per lane-group (no shfl reduce): 230.4us BEST.
//  R22 (FAILED): xin A-frags direct from global = 16-line scattered reads,
//       latency exposed at low occ (linear2 43us, Occ 18%, HBM 8%). LDS
//       staging exists to coalesce exactly that pattern — keep it.
//  R23 (this round): occupancy via TILE HEIGHT: BM 128->64. LDS 69.6->34.8KB
//       (K=128) -> 4 blocks/CU; acc halves (-32 VGPR); grid 782->1563 (tail
//       granularity); staging stays coalesced single-barrier. Gathers = R20.

// ---------------- shared device phase bodies ---------------------------------

__device__ inline void scan256(int* ss, int t) {
#pragma unroll
    for (int off = 1; off < 256; off <<= 1) {
        int u = (t >= off) ? ss[t - off] : 0;
        __syncthreads();
        ss[t] += u;
        __syncthreads();
    }
}

// phase A: hist | cvt_x | cvt_w | zero(pooled) | gstart
__global__ __launch_bounds__(256) void k_phase_a(
    const int* __restrict__ dst, int* __restrict__ bhist, int E,
    const float* __restrict__ x, unsigned short* __restrict__ xb,
    unsigned char* __restrict__ xf8, int nX,
    const float* __restrict__ Wl1, const float* __restrict__ Wr1,
    const float* __restrict__ Wl2, const float* __restrict__ Wr2,
    unsigned short* __restrict__ wbuf,
    float* __restrict__ pooled,
    const int* __restrict__ batch, int* __restrict__ gstart, int N, int G,
    int bHist, int bCvtX, int bCvtW, int bZero) {
    __shared__ int h[256];
    int b = blockIdx.x;
    int tid = threadIdx.x;
    if (b < bHist) {
        h[tid] = 0;
        __syncthreads();
        int e = b * EPB + tid * 4;
        if (e + 3 < E) {
            int4 d4 = *(const int4*)(dst + e);
            atomicAdd(&h[d4.x >> BSH], 1);
            atomicAdd(&h[d4.y >> BSH], 1);
            atomicAdd(&h[d4.z >> BSH], 1);
            atomicAdd(&h[d4.w >> BSH], 1);
        } else {
            for (int k = e; k < E; ++k) atomicAdd(&h[dst[k] >> BSH], 1);
        }
        __syncthreads();
        bhist[(size_t)b * 256 + tid] = h[tid];
    } else if (b < bHist + bCvtX) {
        int i = ((b - bHist) * 256 + tid) * 8;
        if (i < nX) {
            float4 v0 = *(const float4*)(x + i);
            float4 v1 = *(const float4*)(x + i + 4);
            uint4 ob;
            ob.x = pack2(v0.x, v0.y);
            ob.y = pack2(v0.z, v0.w);
            ob.z = pack2(v1.x, v1.y);
            ob.w = pack2(v1.z, v1.w);
            *(uint4*)(xb + i) = ob;
            uint2 of;
            of.x = enc4_fp8(v0.x, v0.y, v0.z, v0.w);
            of.y = enc4_fp8(v1.x, v1.y, v1.z, v1.w);
            *(uint2*)(xf8 + i) = of;
        }
    } else if (b < bHist + bCvtX + bCvtW) {
        int i = (b - bHist - bCvtX) * 256 + tid;
        if (i < 49152) {
            float v;
            if (i < 8192)       v = Wl1[i];
            else if (i < 16384) v = Wr1[i - 8192];
            else if (i < 32768) v = Wl2[i - 16384];
            else                v = Wr2[i - 32768];
            wbuf[i] = f2b(v);
        }
    } else if (b < bHist + bCvtX + bCvtW + bZero) {
        // zero pooled[256][128] (32768 floats) — consumed by linear2 atomics
        int i = ((b - bHist - bCvtX - bCvtW) * 256 + tid) * 4;
        float4 z = make_float4(0.f, 0.f, 0.f, 0.f);
        *(float4*)(pooled + i) = z;
    } else {
        for (int g = tid; g <= G; g += 256) {
            if (g == G) { gstart[G] = N; continue; }
            int lo = 0, hi = N;
            while (lo < hi) {
                int mid = (lo + hi) >> 1;
                if (batch[mid] < g) lo = mid + 1; else hi = mid;
            }
            gstart[g] = lo;
        }
    }
}

// column scan: for bucket k, exclusive-prefix bhist[:,k] over blocks; btot[k]=total
__global__ __launch_bounds__(256) void k_scan_bh(int* __restrict__ bhist,
                                                 int* __restrict__ btot, int nb) {
    __shared__ int ss[256];
    int k = blockIdx.x;
    int t = threadIdx.x;
    int b0 = t * 4;
    int v[4];
    int sum = 0;
#pragma unroll
    for (int i = 0; i < 4; ++i) {
        int b = b0 + i;
        v[i] = (b < nb) ? bhist[(size_t)b * 256 + k] : 0;
        sum += v[i];
    }
    ss[t] = sum;
    __syncthreads();
    scan256(ss, t);
    int run = ss[t] - sum;
#pragma unroll
    for (int i = 0; i < 4; ++i) {
        int b = b0 + i;
        if (b < nb) { bhist[(size_t)b * 256 + k] = run; run += v[i]; }
    }
    if (t == 0) btot[k] = ss[255];
}

// scatter edges into bucket-grouped ebuf; positions via LDS cursors.
// bucket bases recomputed locally from btot. record = (dst&511)<<23 | src
__global__ __launch_bounds__(256) void k_scatter_b(
    const int* __restrict__ src, const int* __restrict__ dst,
    const int* __restrict__ bhist, const int* __restrict__ btot,
    int* __restrict__ ebuf, int E) {
    __shared__ int ss[256];
    __shared__ int lbase[256];
    int b = blockIdx.x;
    int t = threadIdx.x;
    int v = btot[t];
    ss[t] = v;
    __syncthreads();
    scan256(ss, t);
    lbase[t] = (ss[t] - v) + bhist[(size_t)b * 256 + t];
    __syncthreads();
    int e = b * EPB + t * 4;
    if (e + 3 < E) {
        int4 d4 = *(const int4*)(dst + e);
        int4 s4 = *(const int4*)(src + e);
        int k, p;
        k = d4.x >> BSH; p = atomicAdd(&lbase[k], 1); ebuf[p] = ((d4.x & 511) << 23) | s4.x;
        k = d4.y >> BSH; p = atomicAdd(&lbase[k], 1); ebuf[p] = ((d4.y & 511) << 23) | s4.y;
        k = d4.z >> BSH; p = atomicAdd(&lbase[k], 1); ebuf[p] = ((d4.z & 511) << 23) | s4.z;
        k = d4.w >> BSH; p = atomicAdd(&lbase[k], 1); ebuf[p] = ((d4.w & 511) << 23) | s4.w;
    } else {
        for (int q = e; q < E; ++q) {
            int d = dst[q];
            int p = atomicAdd(&lbase[d >> BSH], 1);
            ebuf[p] = ((d & 511) << 23) | src[q];
        }
    }
}

// per-bucket counting sort: 512-bin LDS histogram + scan -> row_start + csr_src
__global__ __launch_bounds__(256) void k_bucket_csr(
    const int* __restrict__ ebuf, const int* __restrict__ btot,
    int* __restrict__ row_start, int* __restrict__ csr_src, int N, int NB) {
    __shared__ int ss[256];
    __shared__ int bbS[257];
    __shared__ int h2[512];
    int k = blockIdx.x;
    int t = threadIdx.x;
    int v = btot[t];
    ss[t] = v;
    __syncthreads();
    scan256(ss, t);
    bbS[t] = ss[t] - v;
    if (t == 255) bbS[256] = ss[255];
    __syncthreads();
    int s = bbS[k], e = bbS[k + 1];
    int node0 = k << BSH;
    int nn = N - node0; if (nn > 512) nn = 512;
    if (k == NB - 1 && t == 0) row_start[node0 + nn] = e;
    h2[t] = 0; h2[t + 256] = 0;
    __syncthreads();
    for (int i = s + t; i < e; i += 256)
        atomicAdd(&h2[((uint)ebuf[i]) >> 23], 1);
    __syncthreads();
    int a0 = h2[2 * t], a1 = h2[2 * t + 1];
    int ps = a0 + a1;
    ss[t] = ps;
    __syncthreads();
    scan256(ss, t);
    int base = ss[t] - ps;
    h2[2 * t] = base;
    h2[2 * t + 1] = base + a0;
    __syncthreads();
    int rs0 = h2[t];
    int rs1 = h2[t + 256];
    __syncthreads();
    if (t < nn)       row_start[node0 + t]       = s + rs0;
    if (t + 256 < nn) row_start[node0 + t + 256] = s + rs1;
    for (int i = s + t; i < e; i += 256) {
        int rec = ebuf[i];
        int j = ((uint)rec) >> 23;
        int pos = atomicAdd(&h2[j], 1);
        csr_src[s + pos] = rec & 0x7FFFFF;
    }
}

// ---------------- mean aggregation (fp8 in, bf16 out, fp32 accumulate) -------
// R20: 1 node per LANE-GROUP: no cross-lane reduce, every lane packs/stores
// its own 8 outputs. Serial edge loop, 2-deep unroll for MLP.

#define ACCF8(v)                                                        \
    { floatx2 f = __builtin_amdgcn_cvt_pk_f32_fp8((v).x, false);        \
      a[0] += f[0]; a[1] += f[1];                                       \
      f = __builtin_amdgcn_cvt_pk_f32_fp8((v).x, true);                 \
      a[2] += f[0]; a[3] += f[1];                                       \
      f = __builtin_amdgcn_cvt_pk_f32_fp8((v).y, false);                \
      a[4] += f[0]; a[5] += f[1];                                       \
      f = __builtin_amdgcn_cvt_pk_f32_fp8((v).y, true);                 \
      a[6] += f[0]; a[7] += f[1]; }

// K=64: 8 lanes per node (8B each), 32 nodes per 256-thread block.
__global__ void k_gather1(const unsigned char* __restrict__ xf8,
                          const int* __restrict__ row_start,
                          const int* __restrict__ csr_src,
                          unsigned short* __restrict__ agg, int n_nodes) {
    int tid = threadIdx.x;
    int node = blockIdx.x * 32 + (tid >> 3);
    if (node >= n_nodes) return;
    int lp = tid & 7;
    int s = row_start[node];
    int e = row_start[node + 1];
    float a[8];
#pragma unroll
    for (int q = 0; q < 8; ++q) a[q] = 0.f;
    int i = s;
    for (; i + 1 < e; i += 2) {
        int u0 = csr_src[i];
        int u1 = csr_src[i + 1];
        uint2 v0 = *(const uint2*)(xf8 + (size_t)u0 * 64 + lp * 8);
        uint2 v1 = *(const uint2*)(xf8 + (size_t)u1 * 64 + lp * 8);
        ACCF8(v0);
        ACCF8(v1);
    }
    if (i < e) {
        int u0 = csr_src[i];
        uint2 v0 = *(const uint2*)(xf8 + (size_t)u0 * 64 + lp * 8);
        ACCF8(v0);
    }
    int d = e - s;
    float scale = (d > 0) ? (1.f / (float)d) : 1.f;
    uint4 o;
    o.x = pack2(a[0] * scale, a[1] * scale);
    o.y = pack2(a[2] * scale, a[3] * scale);
    o.z = pack2(a[4] * scale, a[5] * scale);
    o.w = pack2(a[6] * scale, a[7] * scale);
    *(uint4*)(agg + (size_t)node * 64 + lp * 8) = o;
}

// K=128: 16 lanes per node (8B each), 16 nodes per 256-thread block.
__global__ void k_gather2(const unsigned char* __restrict__ h1f8,
                          const int* __restrict__ row_start,
                          const int* __restrict__ csr_src,
                          unsigned short* __restrict__ agg, int n_nodes) {
    int tid = threadIdx.x;
    int node = blockIdx.x * 16 + (tid >> 4);
    if (node >= n_nodes) return;
    int lp = tid & 15;
    int s = row_start[node];
    int e = row_start[node + 1];
    float a[8];
#pragma unroll
    for (int q = 0; q < 8; ++q) a[q] = 0.f;
    int i = s;
    for (; i + 1 < e; i += 2) {
        int u0 = csr_src[i];
        int u1 = csr_src[i + 1];
        uint2 v0 = *(const uint2*)(h1f8 + (size_t)u0 * 128 + lp * 8);
        uint2 v1 = *(const uint2*)(h1f8 + (size_t)u1 * 128 + lp * 8);
        ACCF8(v0);
        ACCF8(v1);
    }
    if (i < e) {
        int u0 = csr_src[i];
        uint2 v0 = *(const uint2*)(h1f8 + (size_t)u0 * 128 + lp * 8);
        ACCF8(v0);
    }
    int d = e - s;
    float scale = (d > 0) ? (1.f / (float)d) : 1.f;
    uint4 o;
    o.x = pack2(a[0] * scale, a[1] * scale);
    o.y = pack2(a[2] * scale, a[3] * scale);
    o.z = pack2(a[4] * scale, a[5] * scale);
    o.w = pack2(a[6] * scale, a[7] * scale);
    *(uint4*)(agg + (size_t)node * 128 + lp * 8) = o;
}

// ---------------- MFMA SAGE linear: relu(agg@Wl.T + bl + xin@Wr.T) ----------
// R23: BM=64 rows per block. FULL-TILE staging of both operands (coalesced,
// one barrier), LDS 34.8KB @K=128 -> 4 blocks/CU (8 @K=64). acc[4][2].
// Rows padded to K+8 shorts (bank spread).
// POOL=false: emit bf16 h + fp8 copy. POOL=true: R2-validated epilogue —
// per-thread running per-graph sums + atomicAdd into pooled[G][128].

template <int K, bool POOL>
__global__ __launch_bounds__(256) void k_linear_mfma(
    const unsigned short* __restrict__ aggA, const unsigned short* __restrict__ xinA,
    const unsigned short* __restrict__ Wlb,  const float* __restrict__ bl,
    const unsigned short* __restrict__ Wrb,  unsigned short* __restrict__ out,
    unsigned char* __restrict__ outf8,
    const int* __restrict__ batch, float* __restrict__ pooled, int n_nodes) {
    constexpr int NCH = (2 * K) / 32;
    constexpr int KP = K + 8;              // padded row (shorts)
    constexpr int SLOTS = K / 8;           // uint4 slots per row
    __shared__ __align__(16) short As[2 * 64 * KP];  // K=64: 18.4KB, K=128: 34.8KB
    __shared__ int bb[64];

    int tid  = threadIdx.x;
    int lane = tid & 63;
    int wave = tid >> 6;
    int quad = lane >> 4;
    int lr   = lane & 15;
    int node0 = blockIdx.x * 64;

    if (POOL && tid < 64) {
        int n = node0 + tid;
        bb[tid] = (n < n_nodes) ? batch[n] : 0;
    }

    // ---- stage both 64-row tiles, all loads in flight, one barrier ----------
#pragma unroll
    for (int idx = tid; idx < 64 * SLOTS; idx += 256) {
        int row  = idx / SLOTS;
        int slot = idx % SLOTS;
        int n = node0 + row; if (n >= n_nodes) n = n_nodes - 1;
        uint4 va = *(const uint4*)(aggA + (size_t)n * K + slot * 8);
        uint4 vx = *(const uint4*)(xinA + (size_t)n * K + slot * 8);
        *(uint4*)(&As[row * KP + slot * 8]) = va;
        *(uint4*)(&As[64 * KP + row * KP + slot * 8]) = vx;
    }
    __syncthreads();

    floatx4 acc[4][2];
#pragma unroll
    for (int mi = 0; mi < 4; ++mi)
#pragma unroll
        for (int ni = 0; ni < 2; ++ni)
            acc[mi][ni] = (floatx4){0.f, 0.f, 0.f, 0.f};

#pragma unroll
    for (int c = 0; c < NCH; ++c) {
        const unsigned short* srcW = (c < K / 32) ? Wlb : Wrb;
        int base = (c < K / 32) ? 0 : 64 * KP;
        int kb   = (c < K / 32) ? c * 32 : (c - K / 32) * 32;

        short8_t bfrag[2];
#pragma unroll
        for (int ni = 0; ni < 2; ++ni) {
            int j = wave * 32 + ni * 16 + lr;
            bfrag[ni] = *(const short8_t*)(srcW + (size_t)j * K + kb + quad * 8);
        }
#pragma unroll
        for (int mi = 0; mi < 4; ++mi) {
            short8_t af = *(const short8_t*)(&As[base + (mi * 16 + lr) * KP + kb + quad * 8]);
            acc[mi][0] = __builtin_amdgcn_mfma_f32_16x16x32_bf16(af, bfrag[0], acc[mi][0], 0, 0, 0);
            acc[mi][1] = __builtin_amdgcn_mfma_f32_16x16x32_bf16(af, bfrag[1], acc[mi][1], 0, 0, 0);
        }
    }

    float b0 = bl[wave * 32 + lr];
    float b1 = bl[wave * 32 + 16 + lr];
    int j0 = wave * 32 + lr;

    if (!POOL) {
#pragma unroll
        for (int mi = 0; mi < 4; ++mi) {
#pragma unroll
            for (int r = 0; r < 4; ++r) {
                int node = node0 + mi * 16 + quad * 4 + r;
                if (node < n_nodes) {
                    float v0 = fmaxf(acc[mi][0][r] + b0, 0.f);
                    float v1 = fmaxf(acc[mi][1][r] + b1, 0.f);
                    out[(size_t)node * 128 + j0]      = f2b(v0);
                    out[(size_t)node * 128 + j0 + 16] = f2b(v1);
                    outf8[(size_t)node * 128 + j0]      = enc1_fp8(v0);
                    outf8[(size_t)node * 128 + j0 + 16] = enc1_fp8(v1);
                }
            }
        }
    } else {
        // R2-validated: thread's nodes are monotone -> running per-graph sums,
        // flush on boundary; ~1-2 graphs per 64-node window (batch sorted).
        int gcur = -1;
        float s0 = 0.f, s1 = 0.f;
#pragma unroll
        for (int mi = 0; mi < 4; ++mi) {
#pragma unroll
            for (int r = 0; r < 4; ++r) {
                int li = mi * 16 + quad * 4 + r;
                int node = node0 + li;
                if (node < n_nodes) {
                    float v0 = fmaxf(acc[mi][0][r] + b0, 0.f);
                    float v1 = fmaxf(acc[mi][1][r] + b1, 0.f);
                    int g = bb[li];
                    if (g != gcur) {
                        if (gcur >= 0) {
                            atomicAdd(&pooled[gcur * 128 + j0], s0);
                            atomicAdd(&pooled[gcur * 128 + j0 + 16], s1);
                        }
                        gcur = g; s0 = 0.f; s1 = 0.f;
                    }
                    s0 += v0;
                    s1 += v1;
                }
            }
        }
        if (gcur >= 0) {
            atomicAdd(&pooled[gcur * 128 + j0], s0);
            atomicAdd(&pooled[gcur * 128 + j0 + 16], s1);
        }
    }
}

// ---------------- tiny head: mean + linear + log_softmax ---------------------

__global__ void k_head(const float* __restrict__ pooled,
                       const int* __restrict__ gstart,
                       const float* __restrict__ Wout,
                       const float* __restrict__ bout,
                       float* __restrict__ out) {
    int g = blockIdx.x;
    int lane = threadIdx.x;  // 64
    float p0 = pooled[g * 128 + lane];
    float p1 = pooled[g * 128 + 64 + lane];
    float d0 = p0 * Wout[lane] + p1 * Wout[64 + lane];
    float d1 = p0 * Wout[128 + lane] + p1 * Wout[192 + lane];
#pragma unroll
    for (int m = 32; m > 0; m >>= 1) {
        d0 += __shfl_xor(d0, m);
        d1 += __shfl_xor(d1, m);
    }
    if (lane == 0) {
        float cnt = (float)(gstart[g + 1] - gstart[g]);
        float inv = (cnt > 0.f) ? (1.f / cnt) : 1.f;
        float l0 = d0 * inv + bout[0];
        float l1 = d1 * inv + bout[1];
        float mx = fmaxf(l0, l1);
        float lse = mx + logf(expf(l0 - mx) + expf(l1 - mx));
        out[g * 2 + 0] = l0 - lse;
        out[g * 2 + 1] = l1 - lse;
    }
}

// ---------------- launch -----------------------------------------------------

static inline size_t alignUp(size_t x, size_t a) { return (x + a - 1) & ~(a - 1); }

extern "C" void kernel_launch(void* const* d_in, const int* in_sizes, int n_in,
                              void* d_out, int out_size, void* d_ws, size_t ws_size,
                              hipStream_t stream) {
    const float* x    = (const float*)d_in[0];
    const int*   ei   = (const int*)d_in[1];
    const int*   batch= (const int*)d_in[2];
    const float* Wl1  = (const float*)d_in[3];
    const float* bl1  = (const float*)d_in[4];
    const float* Wr1  = (const float*)d_in[5];
    const float* Wl2  = (const float*)d_in[6];
    const float* bl2  = (const float*)d_in[7];
    const float* Wr2  = (const float*)d_in[8];
    const float* Wout = (const float*)d_in[9];
    const float* bout = (const float*)d_in[10];
    float* out = (float*)d_out;

    const int N = in_sizes[0] / 64;   // 100000 (must be < 2^23 for record packing)
    const int E = in_sizes[1] / 2;    // 1000000
    const int G = out_size / 2;       // 256

    const int* src = ei;
    const int* dst = ei + E;

    const int bHist = (E + EPB - 1) / EPB;     // 977
    const int NB    = (N + 511) >> BSH;        // 196 coarse buckets
    const int bCvtX = (N * 64 / 8 + 255) / 256;
    const int bCvtW = 192;
    const int bZero = (G * 128 / 4 + 255) / 256;    // 32

    // workspace layout
    char* ws = (char*)d_ws;
    size_t off = 0;
    int*   bhist     = (int*)(ws + off); off = alignUp(off + (size_t)bHist * 256 * 4, 256);
    int*   btot      = (int*)(ws + off); off = alignUp(off + (size_t)257 * 4, 256);
    int*   row_start = (int*)(ws + off); off = alignUp(off + (size_t)(N + 1) * 4, 256);
    int*   ebuf      = (int*)(ws + off); off = alignUp(off + (size_t)E * 4, 256);
    int*   csr_src   = (int*)(ws + off); off = alignUp(off + (size_t)E * 4, 256);
    int*   gstart    = (int*)(ws + off); off = alignUp(off + (size_t)(G + 1) * 4, 256);
    unsigned short* xb   = (unsigned short*)(ws + off); off = alignUp(off + (size_t)N * 64 * 2, 256);
    unsigned char*  xf8  = (unsigned char*)(ws + off);  off = alignUp(off + (size_t)N * 64, 256);
    unsigned short* wbuf = (unsigned short*)(ws + off); off = alignUp(off + (size_t)49152 * 2, 256);
    unsigned short* agg1 = (unsigned short*)(ws + off); off = alignUp(off + (size_t)N * 64 * 2, 256);
    unsigned short* h1   = (unsigned short*)(ws + off); off = alignUp(off + (size_t)N * 128 * 2, 256);
    unsigned char*  h1f8 = (unsigned char*)(ws + off);  off = alignUp(off + (size_t)N * 128, 256);
    unsigned short* agg2 = (unsigned short*)(ws + off); off = alignUp(off + (size_t)N * 128 * 2, 256);
    float*          pooled = (float*)(ws + off); off = alignUp(off + (size_t)G * 128 * 4, 256);
    (void)ws_size;

    unsigned short* Wl1b = wbuf;
    unsigned short* Wr1b = wbuf + 8192;
    unsigned short* Wl2b = wbuf + 16384;
    unsigned short* Wr2b = wbuf + 32768;

    // phase A: LDS bucket histogram + cvt_x + cvt_w + zero(pooled) + graph bounds
    k_phase_a<<<bHist + bCvtX + bCvtW + bZero + 1, 256, 0, stream>>>(
        dst, bhist, E,
        x, xb, xf8, N * 64,
        Wl1, Wr1, Wl2, Wr2, wbuf,
        pooled,
        batch, gstart, N, G,
        bHist, bCvtX, bCvtW, bZero);

    // bucket scans + bucket-grouped scatter + per-bucket counting sort
    k_scan_bh<<<256, 256, 0, stream>>>(bhist, btot, bHist);
    k_scatter_b<<<bHist, 256, 0, stream>>>(src, dst, bhist, btot, ebuf, E);
    k_bucket_csr<<<NB, 256, 0, stream>>>(ebuf, btot, row_start, csr_src, N, NB);

    // layer 1: gather (fp8) -> MFMA linear (emits h1 bf16 + h1f8 fp8)
    k_gather1<<<(N + 31) / 32, 256, 0, stream>>>(xf8, row_start, csr_src, agg1, N);
    k_linear_mfma<64, false><<<(N + 63) / 64, 256, 0, stream>>>(
        agg1, xb, Wl1b, bl1, Wr1b, h1, h1f8, nullptr, nullptr, N);

    // layer 2: gather -> MFMA linear + per-graph pool (fp32 atomics)
    k_gather2<<<(N + 15) / 16, 256, 0, stream>>>(h1f8, row_start, csr_src, agg2, N);
    k_linear_mfma<128, true><<<(N + 63) / 64, 256, 0, stream>>>(
        agg2, h1, Wl2b, bl2, Wr2b, nullptr, nullptr, batch, pooled, N);

    // tiny head: mean + 128->2 linear + log_softmax
    k_head<<<G, 64, 0, stream>>>(pooled, gstart, Wout, bout, out);
}

// Round 10
// 229.618 us; speedup vs baseline: 1.0829x; 1.0361x over previous
//
#include <hip/hip_runtime.h>
#include <hip/hip_bf16.h>
#include <math.h>

typedef short short8_t __attribute__((ext_vector_type(8)));
typedef float floatx4  __attribute__((ext_vector_type(4)));
typedef float floatx2  __attribute__((ext_vector_type(2)));
typedef unsigned int uint;

#define EPB 1024   // edges per histogram/scatter block
#define BSH 9      // 512 nodes per coarse bucket

// ---------------- bf16 helpers (RNE) ----------------------------------------

__device__ inline unsigned short f2b(float f) {
    uint u = __float_as_uint(f);
    u += 0x7fff + ((u >> 16) & 1);
    return (unsigned short)(u >> 16);
}
__device__ inline uint pack2(float a, float b) {
    return (uint)f2b(a) | ((uint)f2b(b) << 16);
}

// ---------------- fp8 (e4m3) helpers -----------------------------------------

__device__ inline uint enc4_fp8(float f0, float f1, float f2, float f3) {
    uint v = __builtin_amdgcn_cvt_pk_fp8_f32(f0, f1, 0, false);
    v = __builtin_amdgcn_cvt_pk_fp8_f32(f2, f3, v, true);
    return v;
}
__device__ inline unsigned short enc2_fp8(float f0, float f1) {
    return (unsigned short)(__builtin_amdgcn_cvt_pk_fp8_f32(f0, f1, 0, false) & 0xffff);
}

// Lesson ledger:
//  R10/R13: GLOBAL atomic histogram pinned ~43-50us. LDS hist + few global
//       atomics per block is the pattern that works.
//  R12: co-scheduling light branches in one grid is free.
//  R11/R14/R15: a latency-bound phase inherits a fused kernel's worst-phase
//       occupancy — per-BLOCK fusion of gather into MFMA collapsed (139us).
//  R9/R21: keep scatter targets PACKED. Sparse/gapped regions re-trigger
//       write amp; dispatch overhead < sparse-region cache cost.
//  R17 (FAILED): coop grid.sync ~350us EACH on 8-XCD gfx950. Never.
//  R18 (FAILED): device-scope fences/tickets per block are mini grid.syncs.
//  R20: gathers -> 1 node per lane-group (no shfl reduce): 230.4us BEST.
//  R22 (FAILED): xin A-frags direct from global = scattered 16-line reads.
//  R23 (FAILED): BM=64 tile: halved per-block MFMA vs fixed staging/epilogue
//       overhead + 2x weight re-reads = +7.5us. BM=128 full-tile is the
//       local optimum for this shape.
//  R24 (this round): exact R20 revert + paired-column linear epilogue:
//       permute weight ROWS at cvt_w (row b32+2*lr+ni -> slot b32+ni*16+lr)
//       so each thread's two outputs are ADJACENT cols (2lr,2lr+1): bf16
//       pair = one dword store, fp8 pair = one ushort store; epilogue store
//       instruction count halves. No memory-structure change.

// ---------------- shared device phase bodies ---------------------------------

__device__ inline void scan256(int* ss, int t) {
#pragma unroll
    for (int off = 1; off < 256; off <<= 1) {
        int u = (t >= off) ? ss[t - off] : 0;
        __syncthreads();
        ss[t] += u;
        __syncthreads();
    }
}

// phase A: hist | cvt_x | cvt_w(permuted rows) | zero(pooled) | gstart
__global__ __launch_bounds__(256) void k_phase_a(
    const int* __restrict__ dst, int* __restrict__ bhist, int E,
    const float* __restrict__ x, unsigned short* __restrict__ xb,
    unsigned char* __restrict__ xf8, int nX,
    const float* __restrict__ Wl1, const float* __restrict__ Wr1,
    const float* __restrict__ Wl2, const float* __restrict__ Wr2,
    unsigned short* __restrict__ wbuf,
    float* __restrict__ pooled,
    const int* __restrict__ batch, int* __restrict__ gstart, int N, int G,
    int bHist, int bCvtX, int bCvtW, int bZero) {
    __shared__ int h[256];
    int b = blockIdx.x;
    int tid = threadIdx.x;
    if (b < bHist) {
        h[tid] = 0;
        __syncthreads();
        int e = b * EPB + tid * 4;
        if (e + 3 < E) {
            int4 d4 = *(const int4*)(dst + e);
            atomicAdd(&h[d4.x >> BSH], 1);
            atomicAdd(&h[d4.y >> BSH], 1);
            atomicAdd(&h[d4.z >> BSH], 1);
            atomicAdd(&h[d4.w >> BSH], 1);
        } else {
            for (int k = e; k < E; ++k) atomicAdd(&h[dst[k] >> BSH], 1);
        }
        __syncthreads();
        bhist[(size_t)b * 256 + tid] = h[tid];
    } else if (b < bHist + bCvtX) {
        int i = ((b - bHist) * 256 + tid) * 8;
        if (i < nX) {
            float4 v0 = *(const float4*)(x + i);
            float4 v1 = *(const float4*)(x + i + 4);
            uint4 ob;
            ob.x = pack2(v0.x, v0.y);
            ob.y = pack2(v0.z, v0.w);
            ob.z = pack2(v1.x, v1.y);
            ob.w = pack2(v1.z, v1.w);
            *(uint4*)(xb + i) = ob;
            uint2 of;
            of.x = enc4_fp8(v0.x, v0.y, v0.z, v0.w);
            of.y = enc4_fp8(v1.x, v1.y, v1.z, v1.w);
            *(uint2*)(xf8 + i) = of;
        }
    } else if (b < bHist + bCvtX + bCvtW) {
        int i = (b - bHist - bCvtX) * 256 + tid;
        if (i < 49152) {
            float v;
            int li, K, segbase;
            if (i < 8192)       { v = Wl1[i];         li = i;         K = 64;  segbase = 0; }
            else if (i < 16384) { v = Wr1[i - 8192];  li = i - 8192;  K = 64;  segbase = 8192; }
            else if (i < 32768) { v = Wl2[i - 16384]; li = i - 16384; K = 128; segbase = 16384; }
            else                { v = Wr2[i - 32768]; li = i - 32768; K = 128; segbase = 32768; }
            int j  = li / K;     // original weight row (= output column)
            int ck = li % K;
            // paired-column permutation: row b32+2*lr+ni -> slot b32+ni*16+lr
            int w = j & 31;
            int s = (j & ~31) + ((w & 1) << 4) + (w >> 1);
            wbuf[segbase + s * K + ck] = f2b(v);
        }
    } else if (b < bHist + bCvtX + bCvtW + bZero) {
        // zero pooled[256][128] (32768 floats) — consumed by linear2 atomics
        int i = ((b - bHist - bCvtX - bCvtW) * 256 + tid) * 4;
        float4 z = make_float4(0.f, 0.f, 0.f, 0.f);
        *(float4*)(pooled + i) = z;
    } else {
        for (int g = tid; g <= G; g += 256) {
            if (g == G) { gstart[G] = N; continue; }
            int lo = 0, hi = N;
            while (lo < hi) {
                int mid = (lo + hi) >> 1;
                if (batch[mid] < g) lo = mid + 1; else hi = mid;
            }
            gstart[g] = lo;
        }
    }
}

// column scan: for bucket k, exclusive-prefix bhist[:,k] over blocks; btot[k]=total
__global__ __launch_bounds__(256) void k_scan_bh(int* __restrict__ bhist,
                                                 int* __restrict__ btot, int nb) {
    __shared__ int ss[256];
    int k = blockIdx.x;
    int t = threadIdx.x;
    int b0 = t * 4;
    int v[4];
    int sum = 0;
#pragma unroll
    for (int i = 0; i < 4; ++i) {
        int b = b0 + i;
        v[i] = (b < nb) ? bhist[(size_t)b * 256 + k] : 0;
        sum += v[i];
    }
    ss[t] = sum;
    __syncthreads();
    scan256(ss, t);
    int run = ss[t] - sum;
#pragma unroll
    for (int i = 0; i < 4; ++i) {
        int b = b0 + i;
        if (b < nb) { bhist[(size_t)b * 256 + k] = run; run += v[i]; }
    }
    if (t == 0) btot[k] = ss[255];
}

// scatter edges into bucket-grouped ebuf; positions via LDS cursors.
// bucket bases recomputed locally from btot. record = (dst&511)<<23 | src
__global__ __launch_bounds__(256) void k_scatter_b(
    const int* __restrict__ src, const int* __restrict__ dst,
    const int* __restrict__ bhist, const int* __restrict__ btot,
    int* __restrict__ ebuf, int E) {
    __shared__ int ss[256];
    __shared__ int lbase[256];
    int b = blockIdx.x;
    int t = threadIdx.x;
    int v = btot[t];
    ss[t] = v;
    __syncthreads();
    scan256(ss, t);
    lbase[t] = (ss[t] - v) + bhist[(size_t)b * 256 + t];
    __syncthreads();
    int e = b * EPB + t * 4;
    if (e + 3 < E) {
        int4 d4 = *(const int4*)(dst + e);
        int4 s4 = *(const int4*)(src + e);
        int k, p;
        k = d4.x >> BSH; p = atomicAdd(&lbase[k], 1); ebuf[p] = ((d4.x & 511) << 23) | s4.x;
        k = d4.y >> BSH; p = atomicAdd(&lbase[k], 1); ebuf[p] = ((d4.y & 511) << 23) | s4.y;
        k = d4.z >> BSH; p = atomicAdd(&lbase[k], 1); ebuf[p] = ((d4.z & 511) << 23) | s4.z;
        k = d4.w >> BSH; p = atomicAdd(&lbase[k], 1); ebuf[p] = ((d4.w & 511) << 23) | s4.w;
    } else {
        for (int q = e; q < E; ++q) {
            int d = dst[q];
            int p = atomicAdd(&lbase[d >> BSH], 1);
            ebuf[p] = ((d & 511) << 23) | src[q];
        }
    }
}

// per-bucket counting sort: 512-bin LDS histogram + scan -> row_start + csr_src
__global__ __launch_bounds__(256) void k_bucket_csr(
    const int* __restrict__ ebuf, const int* __restrict__ btot,
    int* __restrict__ row_start, int* __restrict__ csr_src, int N, int NB) {
    __shared__ int ss[256];
    __shared__ int bbS[257];
    __shared__ int h2[512];
    int k = blockIdx.x;
    int t = threadIdx.x;
    int v = btot[t];
    ss[t] = v;
    __syncthreads();
    scan256(ss, t);
    bbS[t] = ss[t] - v;
    if (t == 255) bbS[256] = ss[255];
    __syncthreads();
    int s = bbS[k], e = bbS[k + 1];
    int node0 = k << BSH;
    int nn = N - node0; if (nn > 512) nn = 512;
    if (k == NB - 1 && t == 0) row_start[node0 + nn] = e;
    h2[t] = 0; h2[t + 256] = 0;
    __syncthreads();
    for (int i = s + t; i < e; i += 256)
        atomicAdd(&h2[((uint)ebuf[i]) >> 23], 1);
    __syncthreads();
    int a0 = h2[2 * t], a1 = h2[2 * t + 1];
    int ps = a0 + a1;
    ss[t] = ps;
    __syncthreads();
    scan256(ss, t);
    int base = ss[t] - ps;
    h2[2 * t] = base;
    h2[2 * t + 1] = base + a0;
    __syncthreads();
    int rs0 = h2[t];
    int rs1 = h2[t + 256];
    __syncthreads();
    if (t < nn)       row_start[node0 + t]       = s + rs0;
    if (t + 256 < nn) row_start[node0 + t + 256] = s + rs1;
    for (int i = s + t; i < e; i += 256) {
        int rec = ebuf[i];
        int j = ((uint)rec) >> 23;
        int pos = atomicAdd(&h2[j], 1);
        csr_src[s + pos] = rec & 0x7FFFFF;
    }
}

// ---------------- mean aggregation (fp8 in, bf16 out, fp32 accumulate) -------
// R20: 1 node per LANE-GROUP: no cross-lane reduce, every lane packs/stores
// its own 8 outputs. Serial edge loop, 2-deep unroll for MLP.

#define ACCF8(v)                                                        \
    { floatx2 f = __builtin_amdgcn_cvt_pk_f32_fp8((v).x, false);        \
      a[0] += f[0]; a[1] += f[1];                                       \
      f = __builtin_amdgcn_cvt_pk_f32_fp8((v).x, true);                 \
      a[2] += f[0]; a[3] += f[1];                                       \
      f = __builtin_amdgcn_cvt_pk_f32_fp8((v).y, false);                \
      a[4] += f[0]; a[5] += f[1];                                       \
      f = __builtin_amdgcn_cvt_pk_f32_fp8((v).y, true);                 \
      a[6] += f[0]; a[7] += f[1]; }

// K=64: 8 lanes per node (8B each), 32 nodes per 256-thread block.
__global__ void k_gather1(const unsigned char* __restrict__ xf8,
                          const int* __restrict__ row_start,
                          const int* __restrict__ csr_src,
                          unsigned short* __restrict__ agg, int n_nodes) {
    int tid = threadIdx.x;
    int node = blockIdx.x * 32 + (tid >> 3);
    if (node >= n_nodes) return;
    int lp = tid & 7;
    int s = row_start[node];
    int e = row_start[node + 1];
    float a[8];
#pragma unroll
    for (int q = 0; q < 8; ++q) a[q] = 0.f;
    int i = s;
    for (; i + 1 < e; i += 2) {
        int u0 = csr_src[i];
        int u1 = csr_src[i + 1];
        uint2 v0 = *(const uint2*)(xf8 + (size_t)u0 * 64 + lp * 8);
        uint2 v1 = *(const uint2*)(xf8 + (size_t)u1 * 64 + lp * 8);
        ACCF8(v0);
        ACCF8(v1);
    }
    if (i < e) {
        int u0 = csr_src[i];
        uint2 v0 = *(const uint2*)(xf8 + (size_t)u0 * 64 + lp * 8);
        ACCF8(v0);
    }
    int d = e - s;
    float scale = (d > 0) ? (1.f / (float)d) : 1.f;
    uint4 o;
    o.x = pack2(a[0] * scale, a[1] * scale);
    o.y = pack2(a[2] * scale, a[3] * scale);
    o.z = pack2(a[4] * scale, a[5] * scale);
    o.w = pack2(a[6] * scale, a[7] * scale);
    *(uint4*)(agg + (size_t)node * 64 + lp * 8) = o;
}

// K=128: 16 lanes per node (8B each), 16 nodes per 256-thread block.
__global__ void k_gather2(const unsigned char* __restrict__ h1f8,
                          const int* __restrict__ row_start,
                          const int* __restrict__ csr_src,
                          unsigned short* __restrict__ agg, int n_nodes) {
    int tid = threadIdx.x;
    int node = blockIdx.x * 16 + (tid >> 4);
    if (node >= n_nodes) return;
    int lp = tid & 15;
    int s = row_start[node];
    int e = row_start[node + 1];
    float a[8];
#pragma unroll
    for (int q = 0; q < 8; ++q) a[q] = 0.f;
    int i = s;
    for (; i + 1 < e; i += 2) {
        int u0 = csr_src[i];
        int u1 = csr_src[i + 1];
        uint2 v0 = *(const uint2*)(h1f8 + (size_t)u0 * 128 + lp * 8);
        uint2 v1 = *(const uint2*)(h1f8 + (size_t)u1 * 128 + lp * 8);
        ACCF8(v0);
        ACCF8(v1);
    }
    if (i < e) {
        int u0 = csr_src[i];
        uint2 v0 = *(const uint2*)(h1f8 + (size_t)u0 * 128 + lp * 8);
        ACCF8(v0);
    }
    int d = e - s;
    float scale = (d > 0) ? (1.f / (float)d) : 1.f;
    uint4 o;
    o.x = pack2(a[0] * scale, a[1] * scale);
    o.y = pack2(a[2] * scale, a[3] * scale);
    o.z = pack2(a[4] * scale, a[5] * scale);
    o.w = pack2(a[6] * scale, a[7] * scale);
    *(uint4*)(agg + (size_t)node * 128 + lp * 8) = o;
}

// ---------------- MFMA SAGE linear: relu(agg@Wl.T + bl + xin@Wr.T) ----------
// R20-exact structure: BM=128, FULL-TILE staging of both operands (coalesced,
// one barrier), sync-free MFMA K-loop, rows padded to K+8 shorts.
// R24: weight rows permuted (see cvt_w) so thread outputs land at ADJACENT
// cols (2lr, 2lr+1): bf16 pair = 1 dword store, fp8 pair = 1 ushort store.
// POOL=false: emit bf16 h + fp8 copy. POOL=true: R2-validated epilogue —
// per-thread running per-graph sums + atomicAdd into pooled[G][128].

template <int K, bool POOL>
__global__ __launch_bounds__(256) void k_linear_mfma(
    const unsigned short* __restrict__ aggA, const unsigned short* __restrict__ xinA,
    const unsigned short* __restrict__ Wlb,  const float* __restrict__ bl,
    const unsigned short* __restrict__ Wrb,  unsigned short* __restrict__ out,
    unsigned char* __restrict__ outf8,
    const int* __restrict__ batch, float* __restrict__ pooled, int n_nodes) {
    constexpr int NCH = (2 * K) / 32;
    constexpr int KP = K + 8;              // padded row (shorts)
    constexpr int SLOTS = K / 8;           // uint4 slots per row
    __shared__ __align__(16) short As[2 * 128 * KP];  // K=64: 36.9KB, K=128: 69.6KB
    __shared__ int bb[128];

    int tid  = threadIdx.x;
    int lane = tid & 63;
    int wave = tid >> 6;
    int quad = lane >> 4;
    int lr   = lane & 15;
    int node0 = blockIdx.x * 128;

    if (POOL && tid < 128) {
        int n = node0 + tid;
        bb[tid] = (n < n_nodes) ? batch[n] : 0;
    }

    // ---- stage both full tiles, all loads in flight, one barrier ------------
#pragma unroll
    for (int idx = tid; idx < 128 * SLOTS; idx += 256) {
        int row  = idx / SLOTS;
        int slot = idx % SLOTS;
        int n = node0 + row; if (n >= n_nodes) n = n_nodes - 1;
        uint4 va = *(const uint4*)(aggA + (size_t)n * K + slot * 8);
        uint4 vx = *(const uint4*)(xinA + (size_t)n * K + slot * 8);
        *(uint4*)(&As[row * KP + slot * 8]) = va;
        *(uint4*)(&As[128 * KP + row * KP + slot * 8]) = vx;
    }
    __syncthreads();

    floatx4 acc[8][2];
#pragma unroll
    for (int mi = 0; mi < 8; ++mi)
#pragma unroll
        for (int ni = 0; ni < 2; ++ni)
            acc[mi][ni] = (floatx4){0.f, 0.f, 0.f, 0.f};

#pragma unroll
    for (int c = 0; c < NCH; ++c) {
        const unsigned short* srcW = (c < K / 32) ? Wlb : Wrb;
        int base = (c < K / 32) ? 0 : 128 * KP;
        int kb   = (c < K / 32) ? c * 32 : (c - K / 32) * 32;

        short8_t bfrag[2];
#pragma unroll
        for (int ni = 0; ni < 2; ++ni) {
            int j = wave * 32 + ni * 16 + lr;   // permuted slot index
            bfrag[ni] = *(const short8_t*)(srcW + (size_t)j * K + kb + quad * 8);
        }
#pragma unroll
        for (int mi = 0; mi < 8; ++mi) {
            short8_t af = *(const short8_t*)(&As[base + (mi * 16 + lr) * KP + kb + quad * 8]);
            acc[mi][0] = __builtin_amdgcn_mfma_f32_16x16x32_bf16(af, bfrag[0], acc[mi][0], 0, 0, 0);
            acc[mi][1] = __builtin_amdgcn_mfma_f32_16x16x32_bf16(af, bfrag[1], acc[mi][1], 0, 0, 0);
        }
    }

    // paired columns: acc[][0] -> col0 = wave*32 + 2*lr, acc[][1] -> col0+1
    int c0 = wave * 32 + (lr << 1);
    float b0 = bl[c0];
    float b1 = bl[c0 + 1];

    if (!POOL) {
#pragma unroll
        for (int mi = 0; mi < 8; ++mi) {
#pragma unroll
            for (int r = 0; r < 4; ++r) {
                int node = node0 + mi * 16 + quad * 4 + r;
                if (node < n_nodes) {
                    float v0 = fmaxf(acc[mi][0][r] + b0, 0.f);
                    float v1 = fmaxf(acc[mi][1][r] + b1, 0.f);
                    *(uint*)(out + (size_t)node * 128 + c0) = pack2(v0, v1);
                    *(unsigned short*)(outf8 + (size_t)node * 128 + c0) = enc2_fp8(v0, v1);
                }
            }
        }
    } else {
        // R2-validated: thread's nodes are monotone -> running per-graph sums,
        // flush on boundary; ~1-2 graphs per 128-node window (batch sorted).
        float w00 = 0.f, w01 = 0.f, w10 = 0.f, w11 = 0.f;
        int gcur = -1;
        float s0 = 0.f, s1 = 0.f;
#pragma unroll
        for (int mi = 0; mi < 8; ++mi) {
#pragma unroll
            for (int r = 0; r < 4; ++r) {
                int li = mi * 16 + quad * 4 + r;
                int node = node0 + li;
                if (node < n_nodes) {
                    float v0 = fmaxf(acc[mi][0][r] + b0, 0.f);
                    float v1 = fmaxf(acc[mi][1][r] + b1, 0.f);
                    int g = bb[li];
                    if (g != gcur) {
                        if (gcur >= 0) {
                            atomicAdd(&pooled[gcur * 128 + c0], s0);
                            atomicAdd(&pooled[gcur * 128 + c0 + 1], s1);
                        }
                        gcur = g; s0 = 0.f; s1 = 0.f;
                    }
                    s0 += v0;
                    s1 += v1;
                }
            }
        }
        if (gcur >= 0) {
            atomicAdd(&pooled[gcur * 128 + c0], s0);
            atomicAdd(&pooled[gcur * 128 + c0 + 1], s1);
        }
        (void)w00; (void)w01; (void)w10; (void)w11;
    }
}

// ---------------- tiny head: mean + linear + log_softmax ---------------------

__global__ void k_head(const float* __restrict__ pooled,
                       const int* __restrict__ gstart,
                       const float* __restrict__ Wout,
                       const float* __restrict__ bout,
                       float* __restrict__ out) {
    int g = blockIdx.x;
    int lane = threadIdx.x;  // 64
    float p0 = pooled[g * 128 + lane];
    float p1 = pooled[g * 128 + 64 + lane];
    float d0 = p0 * Wout[lane] + p1 * Wout[64 + lane];
    float d1 = p0 * Wout[128 + lane] + p1 * Wout[192 + lane];
#pragma unroll
    for (int m = 32; m > 0; m >>= 1) {
        d0 += __shfl_xor(d0, m);
        d1 += __shfl_xor(d1, m);
    }
    if (lane == 0) {
        float cnt = (float)(gstart[g + 1] - gstart[g]);
        float inv = (cnt > 0.f) ? (1.f / cnt) : 1.f;
        float l0 = d0 * inv + bout[0];
        float l1 = d1 * inv + bout[1];
        float mx = fmaxf(l0, l1);
        float lse = mx + logf(expf(l0 - mx) + expf(l1 - mx));
        out[g * 2 + 0] = l0 - lse;
        out[g * 2 + 1] = l1 - lse;
    }
}

// ---------------- launch -----------------------------------------------------

static inline size_t alignUp(size_t x, size_t a) { return (x + a - 1) & ~(a - 1); }

extern "C" void kernel_launch(void* const* d_in, const int* in_sizes, int n_in,
                              void* d_out, int out_size, void* d_ws, size_t ws_size,
                              hipStream_t stream) {
    const float* x    = (const float*)d_in[0];
    const int*   ei   = (const int*)d_in[1];
    const int*   batch= (const int*)d_in[2];
    const float* Wl1  = (const float*)d_in[3];
    const float* bl1  = (const float*)d_in[4];
    const float* Wr1  = (const float*)d_in[5];
    const float* Wl2  = (const float*)d_in[6];
    const float* bl2  = (const float*)d_in[7];
    const float* Wr2  = (const float*)d_in[8];
    const float* Wout = (const float*)d_in[9];
    const float* bout = (const float*)d_in[10];
    float* out = (float*)d_out;

    const int N = in_sizes[0] / 64;   // 100000 (must be < 2^23 for record packing)
    const int E = in_sizes[1] / 2;    // 1000000
    const int G = out_size / 2;       // 256

    const int* src = ei;
    const int* dst = ei + E;

    const int bHist = (E + EPB - 1) / EPB;     // 977
    const int NB    = (N + 511) >> BSH;        // 196 coarse buckets
    const int bCvtX = (N * 64 / 8 + 255) / 256;
    const int bCvtW = 192;
    const int bZero = (G * 128 / 4 + 255) / 256;    // 32

    // workspace layout
    char* ws = (char*)d_ws;
    size_t off = 0;
    int*   bhist     = (int*)(ws + off); off = alignUp(off + (size_t)bHist * 256 * 4, 256);
    int*   btot      = (int*)(ws + off); off = alignUp(off + (size_t)257 * 4, 256);
    int*   row_start = (int*)(ws + off); off = alignUp(off + (size_t)(N + 1) * 4, 256);
    int*   ebuf      = (int*)(ws + off); off = alignUp(off + (size_t)E * 4, 256);
    int*   csr_src   = (int*)(ws + off); off = alignUp(off + (size_t)E * 4, 256);
    int*   gstart    = (int*)(ws + off); off = alignUp(off + (size_t)(G + 1) * 4, 256);
    unsigned short* xb   = (unsigned short*)(ws + off); off = alignUp(off + (size_t)N * 64 * 2, 256);
    unsigned char*  xf8  = (unsigned char*)(ws + off);  off = alignUp(off + (size_t)N * 64, 256);
    unsigned short* wbuf = (unsigned short*)(ws + off); off = alignUp(off + (size_t)49152 * 2, 256);
    unsigned short* agg1 = (unsigned short*)(ws + off); off = alignUp(off + (size_t)N * 64 * 2, 256);
    unsigned short* h1   = (unsigned short*)(ws + off); off = alignUp(off + (size_t)N * 128 * 2, 256);
    unsigned char*  h1f8 = (unsigned char*)(ws + off);  off = alignUp(off + (size_t)N * 128, 256);
    unsigned short* agg2 = (unsigned short*)(ws + off); off = alignUp(off + (size_t)N * 128 * 2, 256);
    float*          pooled = (float*)(ws + off); off = alignUp(off + (size_t)G * 128 * 4, 256);
    (void)ws_size;

    unsigned short* Wl1b = wbuf;
    unsigned short* Wr1b = wbuf + 8192;
    unsigned short* Wl2b = wbuf + 16384;
    unsigned short* Wr2b = wbuf + 32768;

    // phase A: LDS bucket histogram + cvt_x + cvt_w(perm) + zero(pooled) + bounds
    k_phase_a<<<bHist + bCvtX + bCvtW + bZero + 1, 256, 0, stream>>>(
        dst, bhist, E,
        x, xb, xf8, N * 64,
        Wl1, Wr1, Wl2, Wr2, wbuf,
        pooled,
        batch, gstart, N, G,
        bHist, bCvtX, bCvtW, bZero);

    // bucket scans + bucket-grouped scatter + per-bucket counting sort
    k_scan_bh<<<256, 256, 0, stream>>>(bhist, btot, bHist);
    k_scatter_b<<<bHist, 256, 0, stream>>>(src, dst, bhist, btot, ebuf, E);
    k_bucket_csr<<<NB, 256, 0, stream>>>(ebuf, btot, row_start, csr_src, N, NB);

    // layer 1: gather (fp8) -> MFMA linear (emits h1 bf16 + h1f8 fp8)
    k_gather1<<<(N + 31) / 32, 256, 0, stream>>>(xf8, row_start, csr_src, agg1, N);
    k_linear_mfma<64, false><<<(N + 127) / 128, 256, 0, stream>>>(
        agg1, xb, Wl1b, bl1, Wr1b, h1, h1f8, nullptr, nullptr, N);

    // layer 2: gather -> MFMA linear + per-graph pool (fp32 atomics)
    k_gather2<<<(N + 15) / 16, 256, 0, stream>>>(h1f8, row_start, csr_src, agg2, N);
    k_linear_mfma<128, true><<<(N + 127) / 128, 256, 0, stream>>>(
        agg2, h1, Wl2b, bl2, Wr2b, nullptr, nullptr, batch, pooled, N);

    // tiny head: mean + 128->2 linear + log_softmax
    k_head<<<G, 64, 0, stream>>>(pooled, gstart, Wout, bout, out);
}